// Round 1
// baseline (89.905 us; speedup 1.0000x reference)
//
#include <hip/hip_runtime.h>

namespace {

constexpr int IMGSZ = 224;
constexpr int IMG2  = IMGSZ * IMGSZ;   // 50176

// glimpse sizes 12,23,68,135 ; ksz = g - 11 -> 1,12,57,124
// ws layout: per glimpse i: u at ws[i*384 + r] (r<ksz), v at ws[i*384 + 128 + c] (c<ksz)

__global__ __launch_bounds__(128) void prep_kernel(
    const float* __restrict__ k0, const float* __restrict__ k1,
    const float* __restrict__ k2, const float* __restrict__ k3,
    float* __restrict__ ws) {
  const int t = threadIdx.x;
  const float* ks[4] = {k0, k1, k2, k3};
  const int kszs[4] = {1, 12, 57, 124};
  #pragma unroll
  for (int i = 0; i < 4; ++i) {
    const int ksz = kszs[i];
    const float* k = ks[i];          // channel 0 of (1,3,ksz,ksz); channels identical
    if (t < ksz) {
      const int c0 = ksz >> 1;
      const float piv = k[c0 * ksz + c0];
      ws[i * 384 + t]       = k[t * ksz + c0];         // u[r]  (vertical factor)
      ws[i * 384 + 128 + t] = k[c0 * ksz + t] / piv;   // v[c]  (horizontal factor)
    }
  }
}

// Horizontal pass for one wave: rows r_local = lane, output columns OXB..OXB+2.
// vbuf[11 + kx] = v[kx], zero-padded (length 192). s_lds rows zero-padded to col 148.
template <int OXB, int G>
__device__ __forceinline__ void phase2(
    int r_local, int t0,
    const float (*__restrict__ s_lds)[148],
    const float* __restrict__ vbuf,
    float (*__restrict__ tmp_lds)[12]) {
  constexpr int CB = ((G + 11) / 12) * 12;   // padded column loop bound
  float acc[3] = {0.f, 0.f, 0.f};
  float wlo[12], whi[12];
  #pragma unroll
  for (int q = 0; q < 3; ++q) {
    float4 a = *reinterpret_cast<const float4*>(&vbuf[q * 4]);
    wlo[q * 4 + 0] = a.x; wlo[q * 4 + 1] = a.y; wlo[q * 4 + 2] = a.z; wlo[q * 4 + 3] = a.w;
    float4 bb = *reinterpret_cast<const float4*>(&vbuf[12 + q * 4]);
    whi[q * 4 + 0] = bb.x; whi[q * 4 + 1] = bb.y; whi[q * 4 + 2] = bb.z; whi[q * 4 + 3] = bb.w;
  }
  for (int cb = 0; cb < CB; cb += 12) {
    float sv[12];
    #pragma unroll
    for (int q = 0; q < 3; ++q) {
      float4 s4 = *reinterpret_cast<const float4*>(&s_lds[r_local][cb + q * 4]);
      sv[q * 4 + 0] = s4.x; sv[q * 4 + 1] = s4.y; sv[q * 4 + 2] = s4.z; sv[q * 4 + 3] = s4.w;
    }
    #pragma unroll
    for (int j = 0; j < 12; ++j) {
      #pragma unroll
      for (int q = 0; q < 3; ++q) {
        const int tt = 11 + j - (OXB + q);          // compile-time, in [0,22]
        const float vv = (tt < 12) ? wlo[tt] : whi[tt - 12];
        acc[q] += sv[j] * vv;
      }
    }
    #pragma unroll
    for (int q = 0; q < 12; ++q) wlo[q] = whi[q];
    #pragma unroll
    for (int q = 0; q < 3; ++q) {
      float4 bb = *reinterpret_cast<const float4*>(&vbuf[cb + 24 + q * 4]);
      whi[q * 4 + 0] = bb.x; whi[q * 4 + 1] = bb.y; whi[q * 4 + 2] = bb.z; whi[q * 4 + 3] = bb.w;
    }
  }
  const int grow = t0 + r_local;
  if (grow < G) {
    tmp_lds[grow][OXB + 0] = acc[0];
    tmp_lds[grow][OXB + 1] = acc[1];
    tmp_lds[grow][OXB + 2] = acc[2];
  }
}

template <int G>
__device__ void run_glimpse(
    int b, int gi,
    const float* __restrict__ img, const int* __restrict__ locs,
    const float* __restrict__ ws, float* __restrict__ out,
    float (*s_lds)[148], float (*tmp_lds)[12], float* vbuf, float* ubuf) {
  constexpr int KSZ = G - 11;
  const int tid = threadIdx.x;

  if (tid < 192) {
    float v = 0.f;
    const int kx = tid - 11;
    if (kx >= 0 && kx < KSZ) v = ws[gi * 384 + 128 + kx];
    vbuf[tid] = v;
  }
  if (tid < 128) ubuf[tid] = (tid < KSZ) ? ws[gi * 384 + tid] : 0.f;

  const int x = locs[2 * b];           // row coordinate (H)
  const int y = locs[2 * b + 1];       // col coordinate (W)
  const int row0 = x - G / 2;
  const int col0 = y - G / 2;
  const float* imgb = img + (size_t)b * (3 * IMG2);

  const int wid = tid >> 6;
  const int r_local = tid & 63;

  for (int t0 = 0; t0 < G; t0 += 64) {
    const int nrows = (G - t0) < 64 ? (G - t0) : 64;
    __syncthreads();   // previous phase2 done before overwriting s_lds (also covers vbuf fill)
    // phase 1: channel-summed crop rows [t0, t0+nrows) -> LDS, zero-padded to 148 cols
    for (int idx = tid; idx < nrows * 148; idx += 256) {
      const int r = idx / 148;
      const int c = idx - r * 148;
      float s = 0.f;
      if (c < G) {
        const int row = row0 + t0 + r;
        const int col = col0 + c;
        if ((unsigned)row < (unsigned)IMGSZ && (unsigned)col < (unsigned)IMGSZ) {
          const float* p = imgb + row * IMGSZ + col;
          s = p[0] + p[IMG2] + p[2 * IMG2];
        }
      }
      s_lds[r][c] = s;
    }
    __syncthreads();
    // phase 2: horizontal separable pass (wave-uniform branch, no barriers inside)
    switch (wid) {
      case 0:  phase2<0, G>(r_local, t0, s_lds, vbuf, tmp_lds); break;
      case 1:  phase2<3, G>(r_local, t0, s_lds, vbuf, tmp_lds); break;
      case 2:  phase2<6, G>(r_local, t0, s_lds, vbuf, tmp_lds); break;
      default: phase2<9, G>(r_local, t0, s_lds, vbuf, tmp_lds); break;
    }
  }
  __syncthreads();
  // phase 3: vertical pass
  if (tid < 144) {
    const int oy = tid / 12;
    const int ox = tid - oy * 12;
    float s = 0.f;
    #pragma unroll 4
    for (int ky = 0; ky < KSZ; ++ky) s += tmp_lds[oy + ky][ox] * ubuf[ky];
    out[((size_t)b * 4 + gi) * 144 + tid] = s;
  }
}

__global__ __launch_bounds__(256) void glimpse_kernel(
    const float* __restrict__ img, const int* __restrict__ locs,
    const float* __restrict__ ws, float* __restrict__ out) {
  __shared__ float s_lds[64][148];
  __shared__ float tmp_lds[136][12];
  __shared__ float vbuf[192];
  __shared__ float ubuf[128];
  const int bid = blockIdx.x;
  const int gi = bid & 3;        // interleave glimpse kinds across XCDs
  const int b = bid >> 2;
  switch (gi) {
    case 0:  run_glimpse<12>(b, 0, img, locs, ws, out, s_lds, tmp_lds, vbuf, ubuf); break;
    case 1:  run_glimpse<23 >(b, 1, img, locs, ws, out, s_lds, tmp_lds, vbuf, ubuf); break;
    case 2:  run_glimpse<68 >(b, 2, img, locs, ws, out, s_lds, tmp_lds, vbuf, ubuf); break;
    default: run_glimpse<135>(b, 3, img, locs, ws, out, s_lds, tmp_lds, vbuf, ubuf); break;
  }
}

}  // namespace

extern "C" void kernel_launch(void* const* d_in, const int* in_sizes, int n_in,
                              void* d_out, int out_size, void* d_ws, size_t ws_size,
                              hipStream_t stream) {
  const float* img  = (const float*)d_in[0];
  const int*   locs = (const int*)d_in[1];
  const float* k0   = (const float*)d_in[2];
  const float* k1   = (const float*)d_in[3];
  const float* k2   = (const float*)d_in[4];
  const float* k3   = (const float*)d_in[5];
  float* ws  = (float*)d_ws;
  float* out = (float*)d_out;

  prep_kernel<<<1, 128, 0, stream>>>(k0, k1, k2, k3, ws);
  glimpse_kernel<<<1024, 256, 0, stream>>>(img, locs, ws, out);
}

// Round 2
// 35.295 us; speedup vs baseline: 2.5472x; 2.5472x over previous
//
#include <hip/hip_runtime.h>

namespace {

constexpr int IMGSZ = 224;
constexpr int IMG2  = IMGSZ * IMGSZ;   // 50176
constexpr int SLOT  = 1632;            // per (b,gi) H slot in floats (>= 135*12)
constexpr int PREP_OFF = 256 * 4 * SLOT;          // floats
constexpr int NEED_WS_FLOATS = PREP_OFF + 1536;   // H scratch + factored kernels

// glimpse sizes 12,23,68,135 ; ksz = g - 11 -> 1,12,57,124
// prep area layout (base p): per glimpse i: u at p[i*384 + r] (r<ksz), v at p[i*384 + 128 + c]

__global__ __launch_bounds__(128) void prep_kernel(
    const float* __restrict__ k0, const float* __restrict__ k1,
    const float* __restrict__ k2, const float* __restrict__ k3,
    float* __restrict__ wp) {
  const int t = threadIdx.x;
  const float* ks[4] = {k0, k1, k2, k3};
  const int kszs[4] = {1, 12, 57, 124};
  #pragma unroll
  for (int i = 0; i < 4; ++i) {
    const int ksz = kszs[i];
    const float* k = ks[i];          // channel 0 of (1,3,ksz,ksz); channels identical
    if (t < ksz) {
      const int c0 = ksz >> 1;
      const float piv = k[c0 * ksz + c0];
      wp[i * 384 + t]       = k[t * ksz + c0];         // u[r]  (vertical factor)
      wp[i * 384 + 128 + t] = k[c0 * ksz + t] / piv;   // v[c]  (horizontal factor)
    }
  }
}

// ---------------- new high-occupancy path ----------------

// Horizontal pass: one block = (b, gi, 16-row chunk). H[row][ox] = sum_c S[row][c] * v[c-ox]
template <int G>
__device__ void hpass(
    int b, int gi, int ch,
    const float* __restrict__ img, const int* __restrict__ locs,
    const float* __restrict__ wp, float* __restrict__ H,
    float (*s_lds)[136], float* vpad, float (*part2)[16][13]) {
  constexpr int KSZ = G - 11;
  constexpr int G4  = (G + 3) & ~3;
  constexpr int NCB = G4 / 4;          // 4-col blocks
  const int tid = threadIdx.x;

  // vpad[11+k] = v[k], zeros elsewhere (size 160, covers reads up to c+15 <= 147)
  for (int i = tid; i < 160; i += 128) {
    float v = 0.f;
    const int k = i - 11;
    if (k >= 0 && k < KSZ) v = wp[gi * 384 + 128 + k];
    vpad[i] = v;
  }

  const int x = locs[2 * b];
  const int y = locs[2 * b + 1];
  const int row0 = x - G / 2 + ch * 16;
  const int col0 = y - G / 2;
  const int R = (G - ch * 16) < 16 ? (G - ch * 16) : 16;
  const float* imgb = img + (size_t)b * (3 * IMG2);

  // stage channel-summed rows into LDS (zero-fill rows >= R and cols >= G)
  for (int idx = tid; idx < 16 * G4; idx += 128) {
    const int r = idx / G4;
    const int c = idx - r * G4;
    float s = 0.f;
    if (r < R && c < G) {
      const int row = row0 + r;
      const int col = col0 + c;
      if ((unsigned)row < (unsigned)IMGSZ && (unsigned)col < (unsigned)IMGSZ) {
        const float* p = imgb + row * IMGSZ + col;
        s = p[0] + p[IMG2] + p[2 * IMG2];
      }
    }
    s_lds[r][c] = s;
  }
  __syncthreads();

  const int row = tid & 15;    // lane row
  const int seg = tid >> 4;    // c-segment 0..7
  float acc[12];
  #pragma unroll
  for (int i = 0; i < 12; ++i) acc[i] = 0.f;

  for (int cb = seg; cb < NCB; cb += 8) {
    const int c = cb * 4;
    const float4 s4 = *reinterpret_cast<const float4*>(&s_lds[row][c]);
    float vv[16];
    #pragma unroll
    for (int q = 0; q < 4; ++q) {
      const float4 v4 = *reinterpret_cast<const float4*>(&vpad[c + q * 4]);
      vv[q * 4 + 0] = v4.x; vv[q * 4 + 1] = v4.y; vv[q * 4 + 2] = v4.z; vv[q * 4 + 3] = v4.w;
    }
    const float sj[4] = {s4.x, s4.y, s4.z, s4.w};
    #pragma unroll
    for (int j = 0; j < 4; ++j) {
      #pragma unroll
      for (int ox = 0; ox < 12; ++ox) {
        acc[ox] += sj[j] * vv[11 + j - ox];   // vpad[11 + (c+j) - ox], compile-time reg idx
      }
    }
  }

  // reduce across 8 segments: shfl tree within wave (segs are lane strides of 16)
  #pragma unroll
  for (int ox = 0; ox < 12; ++ox) {
    acc[ox] += __shfl_down(acc[ox], 32, 64);
    acc[ox] += __shfl_down(acc[ox], 16, 64);
  }
  const int lane = tid & 63;
  const int wv = tid >> 6;
  if (lane < 16) {
    #pragma unroll
    for (int ox = 0; ox < 12; ++ox) part2[wv][lane][ox] = acc[ox];
  }
  __syncthreads();
  for (int e = tid; e < 192; e += 128) {
    const int r = e / 12;
    const int ox = e - r * 12;
    if (r < R) {
      H[((size_t)b * 4 + gi) * SLOT + (ch * 16 + r) * 12 + ox] =
          part2[0][r][ox] + part2[1][r][ox];
    }
  }
}

__global__ __launch_bounds__(128) void hpass_kernel(
    const float* __restrict__ img, const int* __restrict__ locs,
    const float* __restrict__ wp, float* __restrict__ H) {
  __shared__ __align__(16) float s_lds[16][136];
  __shared__ __align__(16) float vpad[160];
  __shared__ float part2[2][16][13];
  const int bid = blockIdx.x;
  const int b = bid & 255;
  const int t = bid >> 8;            // 0..16
  int gi, ch;
  if (t == 0)      { gi = 0; ch = 0; }
  else if (t < 3)  { gi = 1; ch = t - 1; }
  else if (t < 8)  { gi = 2; ch = t - 3; }
  else             { gi = 3; ch = t - 8; }
  switch (gi) {
    case 0:  hpass<12 >(b, 0, ch, img, locs, wp, H, s_lds, vpad, part2); break;
    case 1:  hpass<23 >(b, 1, ch, img, locs, wp, H, s_lds, vpad, part2); break;
    case 2:  hpass<68 >(b, 2, ch, img, locs, wp, H, s_lds, vpad, part2); break;
    default: hpass<135>(b, 3, ch, img, locs, wp, H, s_lds, vpad, part2); break;
  }
}

// Vertical pass: out[oy][ox] = sum_ky u[ky] * H[oy+ky][ox]
template <int KSZ>
__device__ void vpass(int b, int gi, const float* __restrict__ ws, float* __restrict__ out) {
  const int tid = threadIdx.x;
  if (tid >= 144) return;
  const int oy = tid / 12;
  const int ox = tid - oy * 12;
  const float* h  = ws + ((size_t)b * 4 + gi) * SLOT + oy * 12 + ox;
  const float* uu = ws + PREP_OFF + gi * 384;
  float s = 0.f;
  #pragma unroll 4
  for (int ky = 0; ky < KSZ; ++ky) s += uu[ky] * h[ky * 12];
  out[((size_t)b * 4 + gi) * 144 + tid] = s;
}

__global__ __launch_bounds__(192) void vpass_kernel(
    const float* __restrict__ ws, float* __restrict__ out) {
  const int bid = blockIdx.x;
  const int gi = bid & 3;
  const int b = bid >> 2;
  switch (gi) {
    case 0:  vpass<1  >(b, 0, ws, out); break;
    case 1:  vpass<12 >(b, 1, ws, out); break;
    case 2:  vpass<57 >(b, 2, ws, out); break;
    default: vpass<124>(b, 3, ws, out); break;
  }
}

// ---------------- fallback path (verified round-1 kernel) ----------------

template <int OXB, int G>
__device__ __forceinline__ void phase2(
    int r_local, int t0,
    const float (*__restrict__ s_lds)[148],
    const float* __restrict__ vbuf,
    float (*__restrict__ tmp_lds)[12]) {
  constexpr int CB = ((G + 11) / 12) * 12;
  float acc[3] = {0.f, 0.f, 0.f};
  float wlo[12], whi[12];
  #pragma unroll
  for (int q = 0; q < 3; ++q) {
    float4 a = *reinterpret_cast<const float4*>(&vbuf[q * 4]);
    wlo[q * 4 + 0] = a.x; wlo[q * 4 + 1] = a.y; wlo[q * 4 + 2] = a.z; wlo[q * 4 + 3] = a.w;
    float4 bb = *reinterpret_cast<const float4*>(&vbuf[12 + q * 4]);
    whi[q * 4 + 0] = bb.x; whi[q * 4 + 1] = bb.y; whi[q * 4 + 2] = bb.z; whi[q * 4 + 3] = bb.w;
  }
  for (int cb = 0; cb < CB; cb += 12) {
    float sv[12];
    #pragma unroll
    for (int q = 0; q < 3; ++q) {
      float4 s4 = *reinterpret_cast<const float4*>(&s_lds[r_local][cb + q * 4]);
      sv[q * 4 + 0] = s4.x; sv[q * 4 + 1] = s4.y; sv[q * 4 + 2] = s4.z; sv[q * 4 + 3] = s4.w;
    }
    #pragma unroll
    for (int j = 0; j < 12; ++j) {
      #pragma unroll
      for (int q = 0; q < 3; ++q) {
        const int tt = 11 + j - (OXB + q);
        const float vv = (tt < 12) ? wlo[tt] : whi[tt - 12];
        acc[q] += sv[j] * vv;
      }
    }
    #pragma unroll
    for (int q = 0; q < 12; ++q) wlo[q] = whi[q];
    #pragma unroll
    for (int q = 0; q < 3; ++q) {
      float4 bb = *reinterpret_cast<const float4*>(&vbuf[cb + 24 + q * 4]);
      whi[q * 4 + 0] = bb.x; whi[q * 4 + 1] = bb.y; whi[q * 4 + 2] = bb.z; whi[q * 4 + 3] = bb.w;
    }
  }
  const int grow = t0 + r_local;
  if (grow < G) {
    tmp_lds[grow][OXB + 0] = acc[0];
    tmp_lds[grow][OXB + 1] = acc[1];
    tmp_lds[grow][OXB + 2] = acc[2];
  }
}

template <int G>
__device__ void run_glimpse(
    int b, int gi,
    const float* __restrict__ img, const int* __restrict__ locs,
    const float* __restrict__ ws, float* __restrict__ out,
    float (*s_lds)[148], float (*tmp_lds)[12], float* vbuf, float* ubuf) {
  constexpr int KSZ = G - 11;
  const int tid = threadIdx.x;
  if (tid < 192) {
    float v = 0.f;
    const int kx = tid - 11;
    if (kx >= 0 && kx < KSZ) v = ws[gi * 384 + 128 + kx];
    vbuf[tid] = v;
  }
  if (tid < 128) ubuf[tid] = (tid < KSZ) ? ws[gi * 384 + tid] : 0.f;
  const int x = locs[2 * b];
  const int y = locs[2 * b + 1];
  const int row0 = x - G / 2;
  const int col0 = y - G / 2;
  const float* imgb = img + (size_t)b * (3 * IMG2);
  const int wid = tid >> 6;
  const int r_local = tid & 63;
  for (int t0 = 0; t0 < G; t0 += 64) {
    const int nrows = (G - t0) < 64 ? (G - t0) : 64;
    __syncthreads();
    for (int idx = tid; idx < nrows * 148; idx += 256) {
      const int r = idx / 148;
      const int c = idx - r * 148;
      float s = 0.f;
      if (c < G) {
        const int row = row0 + t0 + r;
        const int col = col0 + c;
        if ((unsigned)row < (unsigned)IMGSZ && (unsigned)col < (unsigned)IMGSZ) {
          const float* p = imgb + row * IMGSZ + col;
          s = p[0] + p[IMG2] + p[2 * IMG2];
        }
      }
      s_lds[r][c] = s;
    }
    __syncthreads();
    switch (wid) {
      case 0:  phase2<0, G>(r_local, t0, s_lds, vbuf, tmp_lds); break;
      case 1:  phase2<3, G>(r_local, t0, s_lds, vbuf, tmp_lds); break;
      case 2:  phase2<6, G>(r_local, t0, s_lds, vbuf, tmp_lds); break;
      default: phase2<9, G>(r_local, t0, s_lds, vbuf, tmp_lds); break;
    }
  }
  __syncthreads();
  if (tid < 144) {
    const int oy = tid / 12;
    const int ox = tid - oy * 12;
    float s = 0.f;
    #pragma unroll 4
    for (int ky = 0; ky < KSZ; ++ky) s += tmp_lds[oy + ky][ox] * ubuf[ky];
    out[((size_t)b * 4 + gi) * 144 + tid] = s;
  }
}

__global__ __launch_bounds__(256) void glimpse_kernel(
    const float* __restrict__ img, const int* __restrict__ locs,
    const float* __restrict__ ws, float* __restrict__ out) {
  __shared__ __align__(16) float s_lds[64][148];
  __shared__ float tmp_lds[136][12];
  __shared__ __align__(16) float vbuf[192];
  __shared__ float ubuf[128];
  const int bid = blockIdx.x;
  const int gi = bid & 3;
  const int b = bid >> 2;
  switch (gi) {
    case 0:  run_glimpse<12 >(b, 0, img, locs, ws, out, s_lds, tmp_lds, vbuf, ubuf); break;
    case 1:  run_glimpse<23 >(b, 1, img, locs, ws, out, s_lds, tmp_lds, vbuf, ubuf); break;
    case 2:  run_glimpse<68 >(b, 2, img, locs, ws, out, s_lds, tmp_lds, vbuf, ubuf); break;
    default: run_glimpse<135>(b, 3, img, locs, ws, out, s_lds, tmp_lds, vbuf, ubuf); break;
  }
}

}  // namespace

extern "C" void kernel_launch(void* const* d_in, const int* in_sizes, int n_in,
                              void* d_out, int out_size, void* d_ws, size_t ws_size,
                              hipStream_t stream) {
  const float* img  = (const float*)d_in[0];
  const int*   locs = (const int*)d_in[1];
  const float* k0   = (const float*)d_in[2];
  const float* k1   = (const float*)d_in[3];
  const float* k2   = (const float*)d_in[4];
  const float* k3   = (const float*)d_in[5];
  float* ws  = (float*)d_ws;
  float* out = (float*)d_out;

  if (ws_size >= (size_t)NEED_WS_FLOATS * sizeof(float)) {
    prep_kernel<<<1, 128, 0, stream>>>(k0, k1, k2, k3, ws + PREP_OFF);
    hpass_kernel<<<256 * 17, 128, 0, stream>>>(img, locs, ws + PREP_OFF, ws);
    vpass_kernel<<<256 * 4, 192, 0, stream>>>(ws, out);
  } else {
    prep_kernel<<<1, 128, 0, stream>>>(k0, k1, k2, k3, ws);
    glimpse_kernel<<<256 * 4, 256, 0, stream>>>(img, locs, ws, out);
  }
}

// Round 3
// 28.047 us; speedup vs baseline: 3.2055x; 1.2584x over previous
//
#include <hip/hip_runtime.h>

namespace {

constexpr int IMGSZ = 224;
constexpr int IMG2  = IMGSZ * IMGSZ;   // 50176

// One block = (b, 16-row chunk of one glimpse). Computes:
//   H[r][ox] = sum_c S[r][c] * v[c-ox]           (horizontal separable pass)
//   out[oy][ox] += sum_r u[r0+r-oy] * H[r][ox]   (vertical partial, atomic)
// where S = channel-summed crop rows, k = u v^T (rank-1 bicubic kernel),
// u[r] = k[r][c0], v[c] = k[c0][c] / k[c0][c0].
template <int G>
__device__ void chunk_glimpse(
    int b, int gi, int ch,
    const float* __restrict__ img, const int* __restrict__ locs,
    const float* __restrict__ kptr, float* __restrict__ out,
    float (*s_lds)[136], float* vpad, float* upad,
    float (*part2)[16][13], float (*h_lds)[12]) {
  constexpr int KSZ = G - 11;
  constexpr int C0  = KSZ / 2;
  constexpr int G4  = (G + 3) & ~3;
  constexpr int NCB = G4 / 4;          // 4-col blocks
  const int tid = threadIdx.x;
  const int r0 = ch * 16;

  // v (horizontal factor), padded: vpad[11+k] = v[k], zeros elsewhere (size 160)
  {
    const float rpiv = 1.0f / kptr[C0 * KSZ + C0];
    for (int i = tid; i < 160; i += 128) {
      float v = 0.f;
      const int k = i - 11;
      if (k >= 0 && k < KSZ) v = kptr[C0 * KSZ + k] * rpiv;
      vpad[i] = v;
    }
  }
  // u (vertical factor), shifted by 16: upad[16+j] = u[j] for j<KSZ, zeros elsewhere (size 160)
  for (int i = tid; i < 160; i += 128) {
    float u = 0.f;
    const int j = i - 16;
    if (j >= 0 && j < KSZ) u = kptr[j * KSZ + C0];
    upad[i] = u;
  }

  const int x = locs[2 * b];
  const int y = locs[2 * b + 1];
  const int row0 = x - G / 2 + r0;
  const int col0 = y - G / 2;
  const int R = (G - r0) < 16 ? (G - r0) : 16;
  const float* imgb = img + (size_t)b * (3 * IMG2);

  // stage channel-summed rows into LDS (zero-fill rows >= R and cols >= G)
  for (int idx = tid; idx < 16 * G4; idx += 128) {
    const int r = idx / G4;
    const int c = idx - r * G4;
    float s = 0.f;
    if (r < R && c < G) {
      const int row = row0 + r;
      const int col = col0 + c;
      if ((unsigned)row < (unsigned)IMGSZ && (unsigned)col < (unsigned)IMGSZ) {
        const float* p = imgb + row * IMGSZ + col;
        s = p[0] + p[IMG2] + p[2 * IMG2];
      }
    }
    s_lds[r][c] = s;
  }
  __syncthreads();

  // horizontal pass: 16 rows x 8 column-segments
  const int row = tid & 15;
  const int seg = tid >> 4;
  float acc[12];
  #pragma unroll
  for (int i = 0; i < 12; ++i) acc[i] = 0.f;

  for (int cb = seg; cb < NCB; cb += 8) {
    const int c = cb * 4;
    const float4 s4 = *reinterpret_cast<const float4*>(&s_lds[row][c]);
    float vv[16];
    #pragma unroll
    for (int q = 0; q < 4; ++q) {
      const float4 v4 = *reinterpret_cast<const float4*>(&vpad[c + q * 4]);
      vv[q * 4 + 0] = v4.x; vv[q * 4 + 1] = v4.y; vv[q * 4 + 2] = v4.z; vv[q * 4 + 3] = v4.w;
    }
    const float sj[4] = {s4.x, s4.y, s4.z, s4.w};
    #pragma unroll
    for (int j = 0; j < 4; ++j) {
      #pragma unroll
      for (int ox = 0; ox < 12; ++ox) {
        acc[ox] += sj[j] * vv[11 + j - ox];   // vpad[11 + (c+j) - ox], compile-time reg idx
      }
    }
  }

  // reduce the 8 segments: 4 within each wave via shfl (segs sit at lane strides of 16)
  #pragma unroll
  for (int ox = 0; ox < 12; ++ox) {
    acc[ox] += __shfl_down(acc[ox], 32, 64);
    acc[ox] += __shfl_down(acc[ox], 16, 64);
  }
  const int lane = tid & 63;
  const int wv = tid >> 6;
  if (lane < 16) {
    #pragma unroll
    for (int ox = 0; ox < 12; ++ox) part2[wv][lane][ox] = acc[ox];
  }
  __syncthreads();
  for (int e = tid; e < 192; e += 128) {
    const int r = e / 12;
    const int ox = e - r * 12;
    h_lds[r][ox] = (r < R) ? (part2[0][r][ox] + part2[1][r][ox]) : 0.f;
  }
  __syncthreads();

  // vertical partial over this chunk's 16 rows -> atomic scatter into out
  float* outp = out + ((size_t)b * 4 + gi) * 144;
  #pragma unroll
  for (int pass = 0; pass < 2; ++pass) {
    const int e = tid + pass * 128;
    if (e < 144) {
      const int oy = e / 12;
      const int ox = e - oy * 12;
      float s = 0.f;
      #pragma unroll
      for (int r = 0; r < 16; ++r) {
        s += upad[16 + r0 + r - oy] * h_lds[r][ox];
      }
      atomicAdd(&outp[e], s);
    }
  }
}

__global__ __launch_bounds__(128) void glimpse_kernel(
    const float* __restrict__ img, const int* __restrict__ locs,
    const float* __restrict__ k0, const float* __restrict__ k1,
    const float* __restrict__ k2, const float* __restrict__ k3,
    float* __restrict__ out) {
  __shared__ __align__(16) float s_lds[16][136];
  __shared__ __align__(16) float vpad[160];
  __shared__ __align__(16) float upad[160];
  __shared__ float part2[2][16][13];
  __shared__ float h_lds[16][12];
  const int bid = blockIdx.x;
  const int b = bid & 255;
  const int t = bid >> 8;            // 0..16
  if (t == 0) {
    chunk_glimpse<12 >(b, 0, 0,     img, locs, k0, out, s_lds, vpad, upad, part2, h_lds);
  } else if (t < 3) {
    chunk_glimpse<23 >(b, 1, t - 1, img, locs, k1, out, s_lds, vpad, upad, part2, h_lds);
  } else if (t < 8) {
    chunk_glimpse<68 >(b, 2, t - 3, img, locs, k2, out, s_lds, vpad, upad, part2, h_lds);
  } else {
    chunk_glimpse<135>(b, 3, t - 8, img, locs, k3, out, s_lds, vpad, upad, part2, h_lds);
  }
}

}  // namespace

extern "C" void kernel_launch(void* const* d_in, const int* in_sizes, int n_in,
                              void* d_out, int out_size, void* d_ws, size_t ws_size,
                              hipStream_t stream) {
  const float* img  = (const float*)d_in[0];
  const int*   locs = (const int*)d_in[1];
  const float* k0   = (const float*)d_in[2];
  const float* k1   = (const float*)d_in[3];
  const float* k2   = (const float*)d_in[4];
  const float* k3   = (const float*)d_in[5];
  float* out = (float*)d_out;

  hipMemsetAsync(out, 0, (size_t)out_size * sizeof(float), stream);
  glimpse_kernel<<<256 * 17, 128, 0, stream>>>(img, locs, k0, k1, k2, k3, out);
}

// Round 4
// 27.184 us; speedup vs baseline: 3.3072x; 1.0317x over previous
//
#include <hip/hip_runtime.h>

namespace {

constexpr int IMGSZ = 224;
constexpr int IMG2  = IMGSZ * IMGSZ;   // 50176

// One block = (b, 16-row chunk of one glimpse). Per WAVE (2 waves/block, no
// __syncthreads anywhere):
//   lanes = (row 0..15) x (seg 0..3); global seg = wv*4 + seg4 covers 4-col
//   blocks cb = seg, seg+8, ... of the crop, loaded as IMAGE-ALIGNED float4s
//   (channel-summed). H_w[row][ox] = sum_{own cols} S[row][c] * v[c-ox] via
//   compile-time register window against an LDS v-table pre-shifted by
//   sh = col0 & 3. Shfl-reduce 4 segs -> per-wave H partial in LDS ->
//   per-wave vertical partial out[oy][ox] += sum_r u[r0+r-oy]*H[r][ox]
//   scattered with atomicAdd (<=18 adds per address).
// k = u v^T (rank-1 bicubic): u[r] = k[r][c0], v[c] = k[c0][c] / k[c0][c0].
template <int G>
__device__ void chunk_glimpse(
    int b, int gi, int ch,
    const float* __restrict__ img, const int* __restrict__ locs,
    const float* __restrict__ kptr, float* __restrict__ out,
    float* __restrict__ vpad2, float* __restrict__ upad,
    float (*__restrict__ h_lds)[12]) {
  constexpr int KSZ  = G - 11;
  constexpr int C0   = KSZ / 2;
  constexpr int NCB2 = (G + 2) / 4 + 1;    // aligned 4-col blocks (covers sh<=3)
  const int lane = threadIdx.x & 63;
  const int r0 = ch * 16;

  const int x = locs[2 * b];
  const int y = locs[2 * b + 1];
  const int row0 = x - G / 2 + r0;
  const int col0 = y - G / 2;
  const int sh = col0 & 3;                 // floor-mod 4 (works for negative)
  const int col_a0 = col0 - sh;            // image-aligned start (16B aligned)
  const int R = (G - r0) < 16 ? (G - r0) : 16;
  const float* imgb = img + (size_t)b * (3 * IMG2);

  // per-wave v table: vpad2[i] = v[i - 11 - sh], zeros outside [0,KSZ)
  {
    const float rpiv = 1.0f / kptr[C0 * KSZ + C0];
    for (int i = lane; i < 176; i += 64) {
      const int k = i - 11 - sh;
      vpad2[i] = (k >= 0 && k < KSZ) ? kptr[C0 * KSZ + k] * rpiv : 0.f;
    }
  }
  // per-wave u table: upad[16+j] = u[j], zeros outside
  for (int i = lane; i < 160; i += 64) {
    const int j = i - 16;
    upad[i] = (j >= 0 && j < KSZ) ? kptr[j * KSZ + C0] : 0.f;
  }

  const int row = lane & 15;
  const int seg = (threadIdx.x >> 6) * 4 + (lane >> 4);   // 0..7

  float acc[12];
  #pragma unroll
  for (int i = 0; i < 12; ++i) acc[i] = 0.f;

  const int grow = row0 + row;
  if (row < R && (unsigned)grow < (unsigned)IMGSZ) {
    const float* prow = imgb + grow * IMGSZ;
    const int cend = col0 + G;
    for (int cb = seg; cb < NCB2; cb += 8) {
      const int cbase = col_a0 + 4 * cb;
      if (cbase >= cend) break;
      float sj[4];
      if (cbase >= 0 && cbase <= IMGSZ - 4) {
        const float4 a  = *reinterpret_cast<const float4*>(prow + cbase);
        const float4 b4 = *reinterpret_cast<const float4*>(prow + IMG2 + cbase);
        const float4 c4 = *reinterpret_cast<const float4*>(prow + 2 * IMG2 + cbase);
        sj[0] = a.x + b4.x + c4.x;
        sj[1] = a.y + b4.y + c4.y;
        sj[2] = a.z + b4.z + c4.z;
        sj[3] = a.w + b4.w + c4.w;
      } else {
        #pragma unroll
        for (int j = 0; j < 4; ++j) {
          const int cc = cbase + j;
          sj[j] = ((unsigned)cc < (unsigned)IMGSZ)
                      ? prow[cc] + prow[IMG2 + cc] + prow[2 * IMG2 + cc]
                      : 0.f;
        }
      }
      float vv[16];
      #pragma unroll
      for (int q = 0; q < 4; ++q) {
        const float4 v4 = *reinterpret_cast<const float4*>(vpad2 + 4 * cb + 4 * q);
        vv[q * 4 + 0] = v4.x; vv[q * 4 + 1] = v4.y;
        vv[q * 4 + 2] = v4.z; vv[q * 4 + 3] = v4.w;
      }
      #pragma unroll
      for (int j = 0; j < 4; ++j) {
        #pragma unroll
        for (int ox = 0; ox < 12; ++ox) {
          acc[ox] += sj[j] * vv[11 + j - ox];   // = v[c_rel - ox], c_rel = 4cb+j-sh
        }
      }
    }
  }

  // reduce 4 segs within the wave (segs sit at lane strides of 16)
  #pragma unroll
  for (int ox = 0; ox < 12; ++ox) {
    acc[ox] += __shfl_down(acc[ox], 32, 64);
    acc[ox] += __shfl_down(acc[ox], 16, 64);
  }
  if (lane < 16) {
    #pragma unroll
    for (int ox = 0; ox < 12; ++ox) h_lds[lane][ox] = acc[ox];
  }
  // same-wave LDS write->read: ordered by hardware waitcnt, no barrier needed

  // per-wave vertical partial -> atomic scatter
  float* outp = out + ((size_t)b * 4 + gi) * 144;
  for (int e = lane; e < 144; e += 64) {
    const int oy = e / 12;
    const int ox = e - oy * 12;
    float s = 0.f;
    #pragma unroll
    for (int r = 0; r < 16; ++r) {
      s += upad[16 + r0 + r - oy] * h_lds[r][ox];
    }
    atomicAdd(&outp[e], s);
  }
}

__global__ __launch_bounds__(128, 6) void glimpse_kernel(
    const float* __restrict__ img, const int* __restrict__ locs,
    const float* __restrict__ k0, const float* __restrict__ k1,
    const float* __restrict__ k2, const float* __restrict__ k3,
    float* __restrict__ out) {
  __shared__ __align__(16) float vpad2[2][176];
  __shared__ __align__(16) float upad[2][160];
  __shared__ float h_lds[2][16][12];
  const int bid = blockIdx.x;
  const int b = bid & 255;
  const int t = bid >> 8;            // 0..16 ; same-b chunks share an XCD (t*256 % 8 == 0)
  const int wv = threadIdx.x >> 6;
  if (t == 0) {
    chunk_glimpse<12 >(b, 0, 0,     img, locs, k0, out, vpad2[wv], upad[wv], h_lds[wv]);
  } else if (t < 3) {
    chunk_glimpse<23 >(b, 1, t - 1, img, locs, k1, out, vpad2[wv], upad[wv], h_lds[wv]);
  } else if (t < 8) {
    chunk_glimpse<68 >(b, 2, t - 3, img, locs, k2, out, vpad2[wv], upad[wv], h_lds[wv]);
  } else {
    chunk_glimpse<135>(b, 3, t - 8, img, locs, k3, out, vpad2[wv], upad[wv], h_lds[wv]);
  }
}

}  // namespace

extern "C" void kernel_launch(void* const* d_in, const int* in_sizes, int n_in,
                              void* d_out, int out_size, void* d_ws, size_t ws_size,
                              hipStream_t stream) {
  const float* img  = (const float*)d_in[0];
  const int*   locs = (const int*)d_in[1];
  const float* k0   = (const float*)d_in[2];
  const float* k1   = (const float*)d_in[3];
  const float* k2   = (const float*)d_in[4];
  const float* k3   = (const float*)d_in[5];
  float* out = (float*)d_out;

  hipMemsetAsync(out, 0, (size_t)out_size * sizeof(float), stream);
  glimpse_kernel<<<256 * 17, 128, 0, stream>>>(img, locs, k0, k1, k2, k3, out);
}